// Round 2
// baseline (4026.809 us; speedup 1.0000x reference)
//
#include <hip/hip_runtime.h>
#include <math.h>

#if __has_builtin(__builtin_amdgcn_exp2f)
#define EXP2F(x) __builtin_amdgcn_exp2f(x)
#else
#define EXP2F(x) exp2f(x)
#endif

#if __has_builtin(__builtin_amdgcn_logf)
#define LOG2F(x) __builtin_amdgcn_logf(x)
#else
#define LOG2F(x) log2f(x)
#endif

#if __has_builtin(__builtin_amdgcn_rcpf)
#define RCPF(x) __builtin_amdgcn_rcpf(x)
#else
#define RCPF(x) (1.0f / (x))
#endif

#define L2E 1.44269504088896340736f
#define LN2 0.69314718055994530942f

// Native clang vector type for nontemporal builtins (HIP float4 is a class).
typedef float floatx4 __attribute__((ext_vector_type(4)));

// Problem constants
constexpr int V = 32000;
constexpr int H = 8;
constexpr int E = 32;
constexpr int T = 1024;
constexpr int B = 8;
constexpr int TB = T * B;        // 8192 rows
constexpr int V4 = V / 4;        // 8000 float4 per row

// ---------------------------------------------------------------------------
// Kernel A: pre[dir][t][b][h] = emb[x[t,b]] @ Wx + bx[h] + bh[h]
// Fully parallel: 2*T*B*H = 131072 elements.
// ---------------------------------------------------------------------------
__global__ __launch_bounds__(256) void proj_kernel(
    const int* __restrict__ x, const float* __restrict__ emb,
    const float* __restrict__ Wx1, const float* __restrict__ bx1,
    const float* __restrict__ bh1,
    const float* __restrict__ Wx2, const float* __restrict__ bx2,
    const float* __restrict__ bh2,
    float* __restrict__ pre1, float* __restrict__ pre2) {
  int i = blockIdx.x * 256 + threadIdx.x;   // 0 .. 131071
  int dir = i >> 16;                         // uniform per block (blocks 0..255 dir0)
  int j = i & 65535;                         // (t*8+b)*8 + h
  int h = j & 7;
  int tb = j >> 3;
  int idx = x[tb];
  const float* e = emb + (size_t)idx * E;
  const float* Wx = dir ? Wx2 : Wx1;
  float sum = dir ? (bx2[h] + bh2[h]) : (bx1[h] + bh1[h]);
#pragma unroll
  for (int e0 = 0; e0 < E; ++e0) sum = fmaf(e[e0], Wx[e0 * H + h], sum);
  (dir ? pre2 : pre1)[j] = sum;
}

// ---------------------------------------------------------------------------
// Kernel B: the serial recurrences. 1 block, 2 waves (wave = direction).
// DS-FREE design: lane owns the FULL h[8] vector of batch b = lane&7 and
// redundantly computes all 8 outputs in-lane (64 independent fma/step).
// No __shfl / ds_bpermute -> no per-step LDS round-trip latency.
// Lanes 0..15 write th (lane>>3 selects which float4 half).
// pre is prefetched 4 steps ahead as float4 pairs.
// ---------------------------------------------------------------------------
__global__ __launch_bounds__(128) void rnn_kernel(
    const float* __restrict__ pre1, const float* __restrict__ pre2,
    const float* __restrict__ Wh1, const float* __restrict__ Wh2,
    float* __restrict__ th /* [T*B][16] */) {
  const int tid = threadIdx.x;
  const int dir = tid >> 6;
  const int lane = tid & 63;
  const int b = lane & 7;
  const int sel = (lane >> 3) & 1;   // which half this lane stores
  const float4* pre4 = (const float4*)(dir ? pre2 : pre1);  // [T*16] float4
  const float* Wh = dir ? Wh2 : Wh1;
  float4* th4 = (float4*)th;          // [T*B][4] float4

  // Full 8x8 Wh in registers (static indexing only).
  float w[8][8];
#pragma unroll
  for (int i = 0; i < 8; ++i)
#pragma unroll
    for (int j = 0; j < 8; ++j) w[i][j] = Wh[i * H + j];

  float h0 = 0.f, h1 = 0.f, h2 = 0.f, h3 = 0.f;
  float h4 = 0.f, h5 = 0.f, h6 = 0.f, h7 = 0.f;

  constexpr int PF = 4;               // prefetch depth in steps
  float4 cur[PF][2], nxt[PF][2];

#pragma unroll
  for (int u = 0; u < PF; ++u) {
    int s = u;
    int tt = dir ? (T - 1 - s) : s;
    int a = tt * 16 + b * 2;
    cur[u][0] = pre4[a];
    cur[u][1] = pre4[a + 1];
  }

  for (int blk = 0; blk < T / PF; ++blk) {
    int base = blk * PF;
    if (blk < T / PF - 1) {
#pragma unroll
      for (int u = 0; u < PF; ++u) {
        int s = base + PF + u;
        int tt = dir ? (T - 1 - s) : s;
        int a = tt * 16 + b * 2;
        nxt[u][0] = pre4[a];
        nxt[u][1] = pre4[a + 1];
      }
    }
#pragma unroll
    for (int u = 0; u < PF; ++u) {
      int s = base + u;
      int tt = dir ? (T - 1 - s) : s;
      // emit state BEFORE consuming step tt (reference semantics)
      if (lane < 16) {
        float4 v = sel ? make_float4(h4, h5, h6, h7)
                       : make_float4(h0, h1, h2, h3);
        th4[(tt * B + b) * 4 + dir * 2 + sel] = v;
      }
      float a0 = cur[u][0].x, a1 = cur[u][0].y, a2 = cur[u][0].z, a3 = cur[u][0].w;
      float a4 = cur[u][1].x, a5 = cur[u][1].y, a6 = cur[u][1].z, a7 = cur[u][1].w;
      // acc[j] += sum_i h[i] * Wh[i][j]  (8 independent chains -> ILP)
#pragma unroll
      for (int i = 0; i < 8; ++i) {
        float hi = (i == 0) ? h0 : (i == 1) ? h1 : (i == 2) ? h2 : (i == 3) ? h3
                 : (i == 4) ? h4 : (i == 5) ? h5 : (i == 6) ? h6 : h7;
        a0 = fmaf(hi, w[i][0], a0);
        a1 = fmaf(hi, w[i][1], a1);
        a2 = fmaf(hi, w[i][2], a2);
        a3 = fmaf(hi, w[i][3], a3);
        a4 = fmaf(hi, w[i][4], a4);
        a5 = fmaf(hi, w[i][5], a5);
        a6 = fmaf(hi, w[i][6], a6);
        a7 = fmaf(hi, w[i][7], a7);
      }
      h0 = RCPF(1.0f + EXP2F(a0 * -L2E));
      h1 = RCPF(1.0f + EXP2F(a1 * -L2E));
      h2 = RCPF(1.0f + EXP2F(a2 * -L2E));
      h3 = RCPF(1.0f + EXP2F(a3 * -L2E));
      h4 = RCPF(1.0f + EXP2F(a4 * -L2E));
      h5 = RCPF(1.0f + EXP2F(a5 * -L2E));
      h6 = RCPF(1.0f + EXP2F(a6 * -L2E));
      h7 = RCPF(1.0f + EXP2F(a7 * -L2E));
    }
#pragma unroll
    for (int u = 0; u < PF; ++u) {
      cur[u][0] = nxt[u][0];
      cur[u][1] = nxt[u][1];
    }
  }
}

// ---------------------------------------------------------------------------
// Kernel C: logits = th @ output  then log_softmax over V, written to out.
// 16 rows per block; W-tile (16 x float4) in VGPRs, reused across 16 rows.
// Pass 1: online (max, sum-exp). Block-reduce. Pass 2: recompute + write.
// KEY FIX: pass-2 stores are NON-TEMPORAL so the 1 GB output stream does
// not evict the 2 MB Wout from L2 (was: 946 MB of L2 misses at 1.3 TB/s).
// __launch_bounds__(256,3): cap VGPRs (~170) for 3 waves/SIMD.
// ---------------------------------------------------------------------------
__global__ __launch_bounds__(256, 3) void logits_kernel(
    const float* __restrict__ th, const float* __restrict__ Wout,
    float* __restrict__ out) {
  const int tid = threadIdx.x;
  const int row0 = blockIdx.x * 16;

  __shared__ float4 th4[16][4];     // 16 rows x 16 coeffs
  __shared__ float red_m[16][4], red_l[16][4];
  __shared__ float sS[16];

  if (tid < 64) {
    th4[tid >> 2][tid & 3] = ((const float4*)th)[row0 * 4 + tid];
  }
  __syncthreads();

  const float4* W4 = (const float4*)Wout;  // [16][8000]

  float m[16], l[16];
#pragma unroll
  for (int r = 0; r < 16; ++r) { m[r] = -INFINITY; l[r] = 0.f; }

  // ---- Pass 1: online max + sum of exp ----
  for (int v4 = tid; v4 < V4; v4 += 256) {
    float4 w[16];
#pragma unroll
    for (int kk = 0; kk < 16; ++kk) w[kk] = W4[(size_t)kk * V4 + v4];
#pragma unroll
    for (int r = 0; r < 16; ++r) {
      float4 c0 = th4[r][0], c1 = th4[r][1], c2 = th4[r][2], c3 = th4[r][3];
      float cc[16] = {c0.x, c0.y, c0.z, c0.w, c1.x, c1.y, c1.z, c1.w,
                      c2.x, c2.y, c2.z, c2.w, c3.x, c3.y, c3.z, c3.w};
      float ax = 0.f, ay = 0.f, az = 0.f, aw = 0.f;
#pragma unroll
      for (int kk = 0; kk < 16; ++kk) {
        ax = fmaf(w[kk].x, cc[kk], ax);
        ay = fmaf(w[kk].y, cc[kk], ay);
        az = fmaf(w[kk].z, cc[kk], az);
        aw = fmaf(w[kk].w, cc[kk], aw);
      }
      float mx = fmaxf(fmaxf(ax, ay), fmaxf(az, aw));
      float nm = fmaxf(m[r], mx);
      float sc = EXP2F((m[r] - nm) * L2E);
      float s = EXP2F((ax - nm) * L2E) + EXP2F((ay - nm) * L2E) +
                EXP2F((az - nm) * L2E) + EXP2F((aw - nm) * L2E);
      l[r] = fmaf(l[r], sc, s);
      m[r] = nm;
    }
  }

  // ---- Block reduction of (m, l) per row ----
  const int wid = tid >> 6, ln = tid & 63;
#pragma unroll
  for (int r = 0; r < 16; ++r) {
    float mm = m[r], ll = l[r];
#pragma unroll
    for (int off = 32; off > 0; off >>= 1) {
      float om = __shfl_xor(mm, off, 64);
      float ol = __shfl_xor(ll, off, 64);
      float nm = fmaxf(mm, om);
      ll = ll * EXP2F((mm - nm) * L2E) + ol * EXP2F((om - nm) * L2E);
      mm = nm;
    }
    if (ln == 0) { red_m[r][wid] = mm; red_l[r][wid] = ll; }
  }
  __syncthreads();
  if (tid < 16) {
    float mm = red_m[tid][0], ll = red_l[tid][0];
#pragma unroll
    for (int i2 = 1; i2 < 4; ++i2) {
      float om = red_m[tid][i2], ol = red_l[tid][i2];
      float nm = fmaxf(mm, om);
      ll = ll * EXP2F((mm - nm) * L2E) + ol * EXP2F((om - nm) * L2E);
      mm = nm;
    }
    sS[tid] = mm + LOG2F(ll) * LN2;  // m + ln(sum exp(. - m))
  }
  __syncthreads();

  // ---- Pass 2: recompute logits, subtract, write (non-temporal) ----
  floatx4* out4 = (floatx4*)out;
  for (int v4 = tid; v4 < V4; v4 += 256) {
    float4 w[16];
#pragma unroll
    for (int kk = 0; kk < 16; ++kk) w[kk] = W4[(size_t)kk * V4 + v4];
#pragma unroll
    for (int r = 0; r < 16; ++r) {
      float4 c0 = th4[r][0], c1 = th4[r][1], c2 = th4[r][2], c3 = th4[r][3];
      float cc[16] = {c0.x, c0.y, c0.z, c0.w, c1.x, c1.y, c1.z, c1.w,
                      c2.x, c2.y, c2.z, c2.w, c3.x, c3.y, c3.z, c3.w};
      float ax = 0.f, ay = 0.f, az = 0.f, aw = 0.f;
#pragma unroll
      for (int kk = 0; kk < 16; ++kk) {
        ax = fmaf(w[kk].x, cc[kk], ax);
        ay = fmaf(w[kk].y, cc[kk], ay);
        az = fmaf(w[kk].z, cc[kk], az);
        aw = fmaf(w[kk].w, cc[kk], aw);
      }
      float S = sS[r];
      floatx4 o;
      o.x = ax - S; o.y = ay - S; o.z = az - S; o.w = aw - S;
      __builtin_nontemporal_store(o, &out4[(size_t)(row0 + r) * V4 + v4]);
    }
  }
}

// ---------------------------------------------------------------------------
extern "C" void kernel_launch(void* const* d_in, const int* in_sizes, int n_in,
                              void* d_out, int out_size, void* d_ws, size_t ws_size,
                              hipStream_t stream) {
  const int* x = (const int*)d_in[0];
  const float* emb = (const float*)d_in[1];
  const float* Wx1 = (const float*)d_in[2];
  const float* bx1 = (const float*)d_in[3];
  const float* Wh1 = (const float*)d_in[4];
  const float* bh1 = (const float*)d_in[5];
  const float* Wx2 = (const float*)d_in[6];
  const float* bx2 = (const float*)d_in[7];
  const float* Wh2 = (const float*)d_in[8];
  const float* bh2 = (const float*)d_in[9];
  const float* Wout = (const float*)d_in[10];
  float* out = (float*)d_out;

  float* ws = (float*)d_ws;
  float* pre1 = ws;                 // T*B*H = 65536 floats
  float* pre2 = ws + TB * H;        // 65536 floats
  float* th = ws + 2 * TB * H;      // T*B*2H = 131072 floats

  proj_kernel<<<512, 256, 0, stream>>>(x, emb, Wx1, bx1, bh1, Wx2, bx2, bh2,
                                       pre1, pre2);
  rnn_kernel<<<1, 128, 0, stream>>>(pre1, pre2, Wh1, Wh2, th);
  logits_kernel<<<TB / 16, 256, 0, stream>>>(th, Wout, out);
}